// Round 1
// baseline (129.971 us; speedup 1.0000x reference)
//
#include <hip/hip_runtime.h>
#include <math.h>

// Problem constants (B, NA, NO, D, C, T) = (2048, 64, 64, 128, 64, 3)
#define NB 2048
#define NNODES 129
#define ND 128
#define NC 64

// ws float layout:
//  [0]              : mask-dtype flag (int): 0=int32, 1=bytes(bool/int8), 2=float32
//  [16 .. 16+1152)  : u[j*3+i][d]  (9 x 128)   u = W[j] @ a1[i]
//  [1168 .. +384)   : v2[i][d]     (3 x 128)   v2 = W[i] @ a2[i]

__device__ __forceinline__ bool mask_at(const void* m, int flag, int idx) {
  if (flag == 1) return ((const unsigned char*)m)[idx] != 0;
  if (flag == 2) return ((const float*)m)[idx] != 0.0f;
  return ((const int*)m)[idx] != 0;
}

__global__ void hetgat_precomp(const float* __restrict__ W, const float* __restrict__ a,
                               const void* __restrict__ mask, float* __restrict__ ws) {
  int gidx = blockIdx.x * 256 + threadIdx.x;
  if (blockIdx.x == 6) {
    if (threadIdx.x == 0) {
      // Deterministic dtype sniff on first 256 bytes of the mask buffer.
      const unsigned char* mb = (const unsigned char*)mask;
      const unsigned int* mw = (const unsigned int*)mask;
      bool bytes01 = true, words01 = true, wordsF = true;
      for (int i = 0; i < 256; ++i) { if (mb[i] > 1) bytes01 = false; }
      for (int i = 0; i < 64; ++i) {
        unsigned int w = mw[i];
        if (w != 0u && w != 1u) words01 = false;
        if (w != 0u && w != 0x3F800000u) wordsF = false;
      }
      int flag;
      if (words01) flag = 0;        // int32 zeros/ones
      else if (bytes01) flag = 1;   // packed bool / int8
      else if (wordsF) flag = 2;    // float32 0.0/1.0
      else flag = 1;
      ((int*)ws)[0] = flag;
    }
    return;
  }
  if (gidx < 1152) {                // u[j*3+i][d] = sum_c W[j,d,c] * a1[i,c]
    int ji = gidx >> 7, d = gidx & 127;
    int j = ji / 3, i = ji - 3 * j;
    const float4* Wp = (const float4*)(W + j * 8192 + d * 64);
    const float4* ap = (const float4*)(a + i * 128);
    float s = 0.f;
#pragma unroll
    for (int c = 0; c < 16; ++c) {
      float4 w4 = Wp[c], a4 = ap[c];
      s += w4.x * a4.x + w4.y * a4.y + w4.z * a4.z + w4.w * a4.w;
    }
    ws[16 + gidx] = s;
  } else if (gidx < 1536) {         // v2[i][d] = sum_c W[i,d,c] * a2[i,c]
    int rel = gidx - 1152;
    int i = rel >> 7, d = rel & 127;
    const float4* Wp = (const float4*)(W + i * 8192 + d * 64);
    const float4* ap = (const float4*)(a + i * 128 + 64);
    float s = 0.f;
#pragma unroll
    for (int c = 0; c < 16; ++c) {
      float4 w4 = Wp[c], a4 = ap[c];
      s += w4.x * a4.x + w4.y * a4.y + w4.z * a4.z + w4.w * a4.w;
    }
    ws[1168 + rel] = s;
  }
}

// LDS float offsets
#define OFF_HL   0          // 129*128 (XOR-swizzled 16B chunks)
#define OFF_V2L  16512      // 384
#define OFF_ES   16896      // 9
#define OFF_EA   16905      // 192
#define OFF_EO   17097      // 192
#define OFF_WA   17289      // 192
#define OFF_WO   17481      // 192
#define OFF_MSF  17673      // 3
#define OFF_GL   17676      // 384
#define OFF_RED  18060      // 256
#define LDS_FLOATS 18316
#define LDS_BYTES  (LDS_FLOATS * 4)

__global__ __launch_bounds__(256) void hetgat_main(
    const float* __restrict__ h, const float* __restrict__ W,
    const void* __restrict__ mask, const float* __restrict__ ws,
    float* __restrict__ out) {
  extern __shared__ float lds[];
  float* hl  = lds + OFF_HL;
  float* v2l = lds + OFF_V2L;
  float* es  = lds + OFF_ES;
  float* ea  = lds + OFF_EA;
  float* eo  = lds + OFF_EO;
  float* wa  = lds + OFF_WA;
  float* wo  = lds + OFF_WO;
  float* msf = lds + OFF_MSF;
  float* gl  = lds + OFF_GL;
  float* red = lds + OFF_RED;

  const int b = blockIdx.x;
  const int tid = threadIdx.x;
  const int flag = ((const int*)ws)[0];

  // ---- pass 0: stage h[b] (129x128 f32) into LDS, swizzled; stage v2 ----
  const float4* h4 = (const float4*)(h + (size_t)b * NNODES * ND);
  for (int idx = tid; idx < NNODES * 32; idx += 256) {
    int r = idx >> 5, c4 = idx & 31;
    float4 v = h4[idx];
    int pc = c4 ^ (r & 31);
    *((float4*)(hl + r * ND + (pc << 2))) = v;
  }
  if (tid < 96) ((float4*)v2l)[tid] = ((const float4*)(ws + 1168))[tid];
  __syncthreads();

  // ---- pass 1: attention logits ----
  const int wv = tid >> 6;   // wave 0..3
  const int ln = tid & 63;
  if (wv < 3) {
    const int i = wv;                 // type index
    const int ra = 1 + ln;            // ally row
    const int ro = 65 + ln;           // opp row
    const float4* hra = (const float4*)(hl + ra * ND);
    const float4* hro = (const float4*)(hl + ro * ND);
    const float4* vv  = (const float4*)(v2l + i * ND);
    const int sax = ra & 31, sox = ro & 31;
    float sa = 0.f, so = 0.f;
#pragma unroll 8
    for (int c4 = 0; c4 < 32; ++c4) {
      float4 v = vv[c4];
      float4 x = hra[c4 ^ sax];
      float4 y = hro[c4 ^ sox];
      sa += x.x * v.x + x.y * v.y + x.z * v.z + x.w * v.w;
      so += y.x * v.x + y.y * v.y + y.z * v.z + y.w * v.w;
    }
    int mbase = (i * NB + b) * NNODES;
    bool ma = mask_at(mask, flag, mbase + 1 + ln);
    bool mo = mask_at(mask, flag, mbase + 65 + ln);
    ea[i * 64 + ln] = ma ? -INFINITY : sa;
    eo[i * 64 + ln] = mo ? -INFINITY : so;
  } else {
    if (ln < 9) {                     // e_self[j*3+i] = h_self . u[j,i]
      const float4* uu = (const float4*)(ws + 16 + (ln << 7));
      const float4* hs = (const float4*)(hl);   // row 0: swizzle xor = 0
      float s = 0.f;
#pragma unroll 8
      for (int c4 = 0; c4 < 32; ++c4) {
        float4 u4 = uu[c4], x = hs[c4];
        s += x.x * u4.x + x.y * u4.y + x.z * u4.z + x.w * u4.w;
      }
      es[ln] = s;
    } else if (ln < 12) {
      int t = ln - 9;
      msf[t] = mask_at(mask, flag, (t * NB + b) * NNODES) ? 1.f : 0.f;
    }
  }
  __syncthreads();

  // ---- pass 2: collapsed softmax (wave0 = ally, wave1 = opp) ----
  if (wv < 2) {
    float* e = (wv == 0) ? ea : eo;
    float* w = (wv == 0) ? wa : wo;
    float ms[3], S[3];
#pragma unroll
    for (int i = 0; i < 3; ++i) {
      float e0 = es[i], e1 = es[3 + i], e2 = es[6 + i];
      float m = fmaxf(fmaxf(e0, e1), e2);
      ms[i] = m;
      S[i] = expf(e0 - m) + expf(e1 - m) + expf(e2 - m);
    }
    float v0 = e[ln], v1 = e[64 + ln], v2v = e[128 + ln];
    float c0 = v0 + ms[0], c1 = v1 + ms[1], c2 = v2v + ms[2];
    float mx = fmaxf(fmaxf(c0, c1), c2);
    for (int off = 32; off; off >>= 1) mx = fmaxf(mx, __shfl_xor(mx, off));
    float t0 = 0.f, t1 = 0.f, t2 = 0.f;
    if (mx != -INFINITY) {
      t0 = (v0  == -INFINITY) ? 0.f : S[0] * expf(c0 - mx);
      t1 = (v1  == -INFINITY) ? 0.f : S[1] * expf(c1 - mx);
      t2 = (v2v == -INFINITY) ? 0.f : S[2] * expf(c2 - mx);
    }
    float z = t0 + t1 + t2;
    for (int off = 32; off; off >>= 1) z += __shfl_xor(z, off);
    float inv = (z > 0.f) ? 1.f / z : 0.f;
    w[ln] = t0 * inv; w[64 + ln] = t1 * inv; w[128 + ln] = t2 * inv;
  }
  __syncthreads();

  // ---- pass 3: g[t][d] = msf_t*h_self[d] + sum_n (wa[t,n]*h_ally[n,d] + wo[t,n]*h_opp[n,d]) ----
  for (int slot = tid; slot < 384; slot += 256) {
    int t = slot >> 7, d = slot & 127;
    int ch = d >> 2, sub = d & 3;
    float acc = msf[t] * hl[(ch << 2) + sub];   // row 0, swizzle xor 0
    const float* wap = wa + t * 64;
    const float* wop = wo + t * 64;
#pragma unroll 8
    for (int n = 0; n < 64; ++n) {
      int raddr = (1 + n) * ND + (((ch ^ ((1 + n) & 31))) << 2) + sub;
      int oaddr = (65 + n) * ND + (((ch ^ ((65 + n) & 31))) << 2) + sub;
      acc += wap[n] * hl[raddr] + wop[n] * hl[oaddr];
    }
    gl[slot] = acc;
  }
  __syncthreads();

  // ---- epilogue: out[b,c] = elu( sum_t g[t] @ W[t][:,c] ) ----
  {
    int q = tid >> 6, c = tid & 63;
    float acc = 0.f;
#pragma unroll
    for (int t = 0; t < 3; ++t) {
      const float* gp = gl + t * ND;
      const float* Wp = W + t * 8192;
      for (int dd = 32 * q; dd < 32 * q + 32; ++dd) {
        acc += gp[dd] * Wp[dd * 64 + c];
      }
    }
    red[q * 64 + c] = acc;
  }
  __syncthreads();
  if (tid < 64) {
    float x = red[tid] + red[64 + tid] + red[128 + tid] + red[192 + tid];
    out[(size_t)b * NC + tid] = (x > 0.f) ? x : expm1f(x);
  }
}

extern "C" void kernel_launch(void* const* d_in, const int* in_sizes, int n_in,
                              void* d_out, int out_size, void* d_ws, size_t ws_size,
                              hipStream_t stream) {
  (void)in_sizes; (void)n_in; (void)out_size; (void)ws_size;
  const float* h   = (const float*)d_in[0];
  const float* W   = (const float*)d_in[1];
  const float* a   = (const float*)d_in[2];
  const void* mask = d_in[3];
  float* ws  = (float*)d_ws;
  float* out = (float*)d_out;

  // Allow >64KB dynamic LDS (no-op if not required on this runtime).
  (void)hipFuncSetAttribute((const void*)hetgat_main,
                            hipFuncAttributeMaxDynamicSharedMemorySize, LDS_BYTES);

  hetgat_precomp<<<dim3(7), dim3(256), 0, stream>>>(W, a, mask, ws);
  hetgat_main<<<dim3(NB), dim3(256), LDS_BYTES, stream>>>(h, W, mask, ws, out);
}

// Round 2
// 46.940 us; speedup vs baseline: 2.7689x; 2.7689x over previous
//
#include <hip/hip_runtime.h>
#include <hip/hip_bf16.h>
#include <math.h>

// Problem constants (B, NA, NO, D, C, T) = (2048, 64, 64, 128, 64, 3)
#define NB 2048
#define NNODES 129
#define ND 128
#define NC 64

// ws float layout:
//  [0]              : mask-dtype flag (int): 0=int32, 1=bytes(bool/int8), 2=float32
//  [16 .. 16+1152)  : u[j*3+i][d]  (9 x 128)   u = W[j] @ a1[i]
//  [1168 .. +384)   : v2[i][d]     (3 x 128)   v2 = W[i] @ a2[i]

__device__ __forceinline__ bool mask_at(const void* m, int flag, int idx) {
  if (flag == 1) return ((const unsigned char*)m)[idx] != 0;
  if (flag == 2) return ((const float*)m)[idx] != 0.0f;
  return ((const int*)m)[idx] != 0;
}

__global__ void hetgat_precomp(const float* __restrict__ W, const float* __restrict__ a,
                               const void* __restrict__ mask, float* __restrict__ ws) {
  int gidx = blockIdx.x * 256 + threadIdx.x;
  if (blockIdx.x == 6) {
    if (threadIdx.x == 0) {
      const unsigned char* mb = (const unsigned char*)mask;
      const unsigned int* mw = (const unsigned int*)mask;
      bool bytes01 = true, words01 = true, wordsF = true;
      for (int i = 0; i < 256; ++i) { if (mb[i] > 1) bytes01 = false; }
      for (int i = 0; i < 64; ++i) {
        unsigned int w = mw[i];
        if (w != 0u && w != 1u) words01 = false;
        if (w != 0u && w != 0x3F800000u) wordsF = false;
      }
      int flag;
      if (words01) flag = 0;
      else if (bytes01) flag = 1;
      else if (wordsF) flag = 2;
      else flag = 1;
      ((int*)ws)[0] = flag;
    }
    return;
  }
  if (gidx < 1152) {                // u[j*3+i][d] = sum_c W[j,d,c] * a1[i,c]
    int ji = gidx >> 7, d = gidx & 127;
    int j = ji / 3, i = ji - 3 * j;
    const float4* Wp = (const float4*)(W + j * 8192 + d * 64);
    const float4* ap = (const float4*)(a + i * 128);
    float s = 0.f;
#pragma unroll
    for (int c = 0; c < 16; ++c) {
      float4 w4 = Wp[c], a4 = ap[c];
      s += w4.x * a4.x + w4.y * a4.y + w4.z * a4.z + w4.w * a4.w;
    }
    ws[16 + gidx] = s;
  } else if (gidx < 1536) {         // v2[i][d] = sum_c W[i,d,c] * a2[i,c]
    int rel = gidx - 1152;
    int i = rel >> 7, d = rel & 127;
    const float4* Wp = (const float4*)(W + i * 8192 + d * 64);
    const float4* ap = (const float4*)(a + i * 128 + 64);
    float s = 0.f;
#pragma unroll
    for (int c = 0; c < 16; ++c) {
      float4 w4 = Wp[c], a4 = ap[c];
      s += w4.x * a4.x + w4.y * a4.y + w4.z * a4.z + w4.w * a4.w;
    }
    ws[1168 + rel] = s;
  }
}

// h staged in LDS as bf16, row stride 68 u32 (64 data u32 + 2 pad u32, 16B aligned)
#define ROWU 68
// LDS float/u32 offsets
#define OFF_HL   0                    // 129*68 = 8772 u32
#define OFF_V2L  8772                 // 384 f32 (aliased as red later)
#define OFF_ES   9156                 // 9
#define OFF_EA   9168                 // 192  (ea+eo aliased as gl later)
#define OFF_EO   9360                 // 192
#define OFF_WA   9552                 // 192
#define OFF_WO   9744                 // 192
#define OFF_MSF  9936                 // 3
#define LDS_FLOATS 9939               // 39,756 B -> 4 blocks/CU

__device__ __forceinline__ unsigned pack2bf(float a, float b) {
  unsigned short ua = __builtin_bit_cast(unsigned short, __float2bfloat16(a));
  unsigned short ub = __builtin_bit_cast(unsigned short, __float2bfloat16(b));
  return (unsigned)ua | ((unsigned)ub << 16);
}
__device__ __forceinline__ float2 unpack2bf(unsigned w) {
  float lo = __builtin_bit_cast(float, w << 16);
  float hi = __builtin_bit_cast(float, w & 0xffff0000u);
  return make_float2(lo, hi);
}

__global__ __launch_bounds__(256) void hetgat_main(
    const float* __restrict__ h, const float* __restrict__ W,
    const void* __restrict__ mask, const float* __restrict__ ws,
    float* __restrict__ out) {
  __shared__ float lds[LDS_FLOATS];
  unsigned* hlu = (unsigned*)lds;           // bf16x2 words
  float* v2l = lds + OFF_V2L;
  float* es  = lds + OFF_ES;
  float* ea  = lds + OFF_EA;
  float* eo  = lds + OFF_EO;
  float* wa  = lds + OFF_WA;
  float* wo  = lds + OFF_WO;
  float* msf = lds + OFF_MSF;
  float* gl  = lds + OFF_EA;                // alias (pass3+)
  float* red = lds + OFF_V2L;               // alias (epilogue)

  const int b = blockIdx.x;
  const int tid = threadIdx.x;
  const int flag = ((const int*)ws)[0];

  // ---- pass 0: stage h[b] (129x128 f32 -> bf16) into LDS; stage v2 ----
  const float4* h4 = (const float4*)(h + (size_t)b * NNODES * ND);
  for (int idx = tid; idx < NNODES * 32; idx += 256) {
    int r = idx >> 5, c4 = idx & 31;
    float4 v = h4[idx];
    uint2 p;
    p.x = pack2bf(v.x, v.y);
    p.y = pack2bf(v.z, v.w);
    *((uint2*)(hlu + r * ROWU + 2 * c4)) = p;
  }
  if (tid < 96) ((float4*)v2l)[tid] = ((const float4*)(ws + 1168))[tid];
  __syncthreads();

  // ---- pass 1: attention logits ----
  const int wv = tid >> 6;
  const int ln = tid & 63;
  if (wv < 3) {
    const int i = wv;                 // type index
    const int ra = 1 + ln;            // ally row
    const int ro = 65 + ln;           // opp row
    const uint4* hra = (const uint4*)(hlu + ra * ROWU);
    const uint4* hro = (const uint4*)(hlu + ro * ROWU);
    const float4* vv = (const float4*)(v2l + i * ND);
    float sa = 0.f, so = 0.f;
#pragma unroll 4
    for (int c = 0; c < 16; ++c) {
      uint4 xa = hra[c];
      uint4 xo = hro[c];
      float4 v0 = vv[2 * c], v1 = vv[2 * c + 1];
      float2 a0 = unpack2bf(xa.x), a1 = unpack2bf(xa.y), a2 = unpack2bf(xa.z), a3 = unpack2bf(xa.w);
      float2 o0 = unpack2bf(xo.x), o1 = unpack2bf(xo.y), o2 = unpack2bf(xo.z), o3 = unpack2bf(xo.w);
      sa += a0.x * v0.x + a0.y * v0.y + a1.x * v0.z + a1.y * v0.w
          + a2.x * v1.x + a2.y * v1.y + a3.x * v1.z + a3.y * v1.w;
      so += o0.x * v0.x + o0.y * v0.y + o1.x * v0.z + o1.y * v0.w
          + o2.x * v1.x + o2.y * v1.y + o3.x * v1.z + o3.y * v1.w;
    }
    int mbase = (i * NB + b) * NNODES;
    bool ma = mask_at(mask, flag, mbase + 1 + ln);
    bool mo = mask_at(mask, flag, mbase + 65 + ln);
    ea[i * 64 + ln] = ma ? -INFINITY : sa;
    eo[i * 64 + ln] = mo ? -INFINITY : so;
  } else {
    if (ln < 9) {                     // e_self[j*3+i] = h_self . u[j,i]
      const float4* uu = (const float4*)(ws + 16 + (ln << 7));
      const uint4* hs = (const uint4*)(hlu);   // row 0
      float s = 0.f;
#pragma unroll 4
      for (int c = 0; c < 16; ++c) {
        uint4 x = hs[c];
        float4 u0 = uu[2 * c], u1 = uu[2 * c + 1];
        float2 f0 = unpack2bf(x.x), f1 = unpack2bf(x.y), f2 = unpack2bf(x.z), f3 = unpack2bf(x.w);
        s += f0.x * u0.x + f0.y * u0.y + f1.x * u0.z + f1.y * u0.w
           + f2.x * u1.x + f2.y * u1.y + f3.x * u1.z + f3.y * u1.w;
      }
      es[ln] = s;
    } else if (ln < 12) {
      int t = ln - 9;
      msf[t] = mask_at(mask, flag, (t * NB + b) * NNODES) ? 1.f : 0.f;
    }
  }
  __syncthreads();

  // ---- pass 2: collapsed softmax (wave0 = ally, wave1 = opp) ----
  if (wv < 2) {
    float* e = (wv == 0) ? ea : eo;
    float* w = (wv == 0) ? wa : wo;
    float ms[3], S[3];
#pragma unroll
    for (int i = 0; i < 3; ++i) {
      float e0 = es[i], e1 = es[3 + i], e2 = es[6 + i];
      float m = fmaxf(fmaxf(e0, e1), e2);
      ms[i] = m;
      S[i] = expf(e0 - m) + expf(e1 - m) + expf(e2 - m);
    }
    float v0 = e[ln], v1 = e[64 + ln], v2v = e[128 + ln];
    float c0 = v0 + ms[0], c1 = v1 + ms[1], c2 = v2v + ms[2];
    float mx = fmaxf(fmaxf(c0, c1), c2);
    for (int off = 32; off; off >>= 1) mx = fmaxf(mx, __shfl_xor(mx, off));
    float t0 = 0.f, t1 = 0.f, t2 = 0.f;
    if (mx != -INFINITY) {
      t0 = (v0  == -INFINITY) ? 0.f : S[0] * expf(c0 - mx);
      t1 = (v1  == -INFINITY) ? 0.f : S[1] * expf(c1 - mx);
      t2 = (v2v == -INFINITY) ? 0.f : S[2] * expf(c2 - mx);
    }
    float z = t0 + t1 + t2;
    for (int off = 32; off; off >>= 1) z += __shfl_xor(z, off);
    float inv = (z > 0.f) ? 1.f / z : 0.f;
    w[ln] = t0 * inv; w[64 + ln] = t1 * inv; w[128 + ln] = t2 * inv;
  }
  __syncthreads();

  // ---- pass 3: g[t][d] = msf_t*h_self[d] + sum_n (wa[t,n]*h_ally[n,d] + wo[t,n]*h_opp[n,d])
  // 192 threads: ty = tid/64 type, ln = tid&63 owns d = {2ln, 2ln+1}
  if (tid < 192) {
    const int ty = tid >> 6;
    const int l2 = tid & 63;
    float a0, a1;
    {
      float2 f = unpack2bf(hlu[l2]);          // row 0 (self)
      float m = msf[ty];
      a0 = m * f.x; a1 = m * f.y;
    }
    const float* wap = wa + ty * 64;
    const float* wop = wo + ty * 64;
#pragma unroll 4
    for (int n = 0; n < 64; ++n) {
      float2 f = unpack2bf(hlu[(1 + n) * ROWU + l2]);
      float wgt = wap[n];
      a0 += wgt * f.x; a1 += wgt * f.y;
    }
#pragma unroll 4
    for (int n = 0; n < 64; ++n) {
      float2 f = unpack2bf(hlu[(65 + n) * ROWU + l2]);
      float wgt = wop[n];
      a0 += wgt * f.x; a1 += wgt * f.y;
    }
    gl[ty * ND + 2 * l2] = a0;
    gl[ty * ND + 2 * l2 + 1] = a1;
  }
  __syncthreads();

  // ---- epilogue: out[b,c] = elu( sum_t g[t] @ W[t][:,c] ) ----
  {
    int q = tid >> 6, c = tid & 63;
    float acc = 0.f;
#pragma unroll
    for (int t = 0; t < 3; ++t) {
      const float* gp = gl + t * ND;
      const float* Wp = W + t * 8192;
      for (int dd = 32 * q; dd < 32 * q + 32; ++dd) {
        acc += gp[dd] * Wp[dd * 64 + c];
      }
    }
    red[q * 64 + c] = acc;
  }
  __syncthreads();
  if (tid < 64) {
    float x = red[tid] + red[64 + tid] + red[128 + tid] + red[192 + tid];
    out[(size_t)b * NC + tid] = (x > 0.f) ? x : expm1f(x);
  }
}

extern "C" void kernel_launch(void* const* d_in, const int* in_sizes, int n_in,
                              void* d_out, int out_size, void* d_ws, size_t ws_size,
                              hipStream_t stream) {
  (void)in_sizes; (void)n_in; (void)out_size; (void)ws_size;
  const float* h   = (const float*)d_in[0];
  const float* W   = (const float*)d_in[1];
  const float* a   = (const float*)d_in[2];
  const void* mask = d_in[3];
  float* ws  = (float*)d_ws;
  float* out = (float*)d_out;

  hetgat_precomp<<<dim3(7), dim3(256), 0, stream>>>(W, a, mask, ws);
  hetgat_main<<<dim3(NB), dim3(256), 0, stream>>>(h, W, mask, ws, out);
}